// Round 6
// baseline (1063.366 us; speedup 1.0000x reference)
//
#include <hip/hip_runtime.h>
#include <hip/hip_bf16.h>
#include <hip/hip_fp16.h>
#include <math.h>

#define NN 100000
#define EE 1600000
#define MM 20000
#define EPB 6144                        // edges per partition block
#define NBLK ((EE + EPB - 1) / EPB)     // 261 partition blocks
#define NBK ((NN + 127) >> 7)           // 782 buckets of 128 dst nodes
#define N_SCAN (NBK * NBLK + 1)         // 204103 (+ sentinel)
#define SMASK 0xFFFFF                   // low 20 bits: src id

// ---- tiny: v1[16] = We1 @ a_e1 (64), v2[16] = We2 @ a_e2 (32) ----
__global__ void k_v(const float* __restrict__ We1, const float* __restrict__ ae1v,
                    const float* __restrict__ We2, const float* __restrict__ ae2v,
                    float* __restrict__ v1, float* __restrict__ v2) {
    int t = threadIdx.x;
    if (t < 16) {
        float s = 0.f;
        for (int c = 0; c < 64; ++c) s += We1[t * 64 + c] * ae1v[c];
        v1[t] = s;
    } else if (t < 32) {
        int r = t - 16;
        float s = 0.f;
        for (int c = 0; c < 32; ++c) s += We2[r * 32 + c] * ae2v[c];
        v2[r] = s;
    }
}

// ---- layer-1 node transform: hx1 (fp16) = x @ W1, alpha_s/d; zero msk ----
__global__ __launch_bounds__(256) void k_node1(
    const float* __restrict__ x, const float* __restrict__ W,
    const float* __restrict__ a_s, const float* __restrict__ a_d,
    __half* __restrict__ hx, float* __restrict__ aS, float* __restrict__ aD,
    int* __restrict__ msk, int n_nodes)
{
    __shared__ float Wl[64 * 64];
    __shared__ float xs[4][64];
    int tid = threadIdx.x;
#pragma unroll
    for (int i = 0; i < 16; ++i) Wl[tid + i * 256] = W[tid + i * 256];
    int wv = tid >> 6, lane = tid & 63;
    int n = blockIdx.x * 4 + wv;
    bool act = (n < n_nodes);
    if (act) xs[wv][lane] = x[(size_t)n * 64 + lane];
    __syncthreads();
    if (!act) return;
    float h = 0.f;
#pragma unroll
    for (int k = 0; k < 64; ++k) h += xs[wv][k] * Wl[k * 64 + lane];
    hx[(size_t)n * 64 + lane] = __float2half(h);
    float ps = h * a_s[lane];
    float pd = h * a_d[lane];
#pragma unroll
    for (int o = 32; o > 0; o >>= 1) { ps += __shfl_xor(ps, o); pd += __shfl_xor(pd, o); }
    if (lane == 0) { aS[n] = ps; aD[n] = pd; msk[n] = 0; }
}

// ---- scatter mask flags ----
__global__ void k_mask(const int* __restrict__ mask, int* __restrict__ msk, int m_cnt) {
    int m = blockIdx.x * blockDim.x + threadIdx.x;
    if (m < m_cnt) msk[mask[m]] = 1;
}

// ---- per-(bucket,block) histogram (LDS counters, no global atomics) ----
__global__ __launch_bounds__(256) void k_bhist(const int* __restrict__ dst,
                                               int* __restrict__ hist, int E) {
    __shared__ int hl[NBK];
    int tid = threadIdx.x, blk = blockIdx.x;
    for (int j = tid; j < NBK; j += 256) hl[j] = 0;
    __syncthreads();
    int e0 = blk * EPB, e1 = min(E, e0 + EPB);
    for (int e = e0 + tid; e < e1; e += 256) atomicAdd(&hl[dst[e] >> 7], 1);
    __syncthreads();
    for (int j = tid; j < NBK; j += 256) hist[j * NBLK + blk] = hl[j];
    if (blk == 0 && tid == 0) hist[NBK * NBLK] = 0;  // sentinel -> scan yields E
}

// ---- scan kernels: exclusive prefix over hist[0..n) (2048 elems/block) ----
__global__ __launch_bounds__(256) void k_scan1(const int* __restrict__ deg, int* __restrict__ pre,
                                               int* __restrict__ bsum, int n) {
    __shared__ int wsum[4];
    int t = threadIdx.x;
    int base = blockIdx.x * 2048 + t * 8;
    int v[8]; int s = 0;
#pragma unroll
    for (int i = 0; i < 8; ++i) { int idx = base + i; int d = (idx < n) ? deg[idx] : 0; v[i] = s; s += d; }
    int lane = t & 63, wv = t >> 6;
    int incl = s;
#pragma unroll
    for (int off = 1; off < 64; off <<= 1) { int y = __shfl_up(incl, off); if (lane >= off) incl += y; }
    if (lane == 63) wsum[wv] = incl;
    __syncthreads();
    int woff = 0;
    for (int w = 0; w < wv; ++w) woff += wsum[w];
    int texcl = woff + incl - s;
#pragma unroll
    for (int i = 0; i < 8; ++i) { int idx = base + i; if (idx < n) pre[idx] = texcl + v[i]; }
    if (t == 255) bsum[blockIdx.x] = woff + incl;
}

__global__ __launch_bounds__(256) void k_scan2(int* __restrict__ bsum, int nb) {
    __shared__ int ws[4];
    int t = threadIdx.x, lane = t & 63, wv = t >> 6;
    int x = (t < nb) ? bsum[t] : 0;
    int incl = x;
#pragma unroll
    for (int off = 1; off < 64; off <<= 1) { int y = __shfl_up(incl, off); if (lane >= off) incl += y; }
    if (lane == 63) ws[wv] = incl;
    __syncthreads();
    int woff = 0;
    for (int w = 0; w < wv; ++w) woff += ws[w];
    if (t < nb) bsum[t] = woff + incl - x;
}

__global__ void k_scan3(int* __restrict__ pre, const int* __restrict__ bsum, int n) {
    int i = blockIdx.x * 256 + threadIdx.x;
    if (i < n) pre[i] += bsum[i >> 11];
}

// ---- partition pass: edge dots + exp(alpha1), write block-owned bucket segments ----
__global__ __launch_bounds__(256) void k_scatter(
    const float* __restrict__ ea, const float* __restrict__ v1, const float* __restrict__ v2,
    const int* __restrict__ src, const int* __restrict__ dst,
    const float* __restrict__ aS1, const float* __restrict__ aD1,
    const int* __restrict__ scanned, float2* __restrict__ recA,
    float* __restrict__ recB, int E)
{
    __shared__ int cur[NBK];
    int tid = threadIdx.x, blk = blockIdx.x;
    for (int j = tid; j < NBK; j += 256) cur[j] = scanned[j * NBLK + blk];
    __syncthreads();
    int e0 = blk * EPB, e1 = min(E, e0 + EPB);
    for (int e = e0 + tid; e < e1; e += 256) {
        const float* p = ea + (size_t)e * 16;
        float s1 = 0.f, s2 = 0.f;
#pragma unroll
        for (int i = 0; i < 16; ++i) { float t = p[i]; s1 += t * v1[i]; s2 += t * v2[i]; }
        int s = src[e], d = dst[e];
        float a = aS1[s] + aD1[d] + s1;
        a = a > 0.f ? a : 0.2f * a;
        int pos = atomicAdd(&cur[d >> 7], 1);
        recA[pos] = make_float2(__int_as_float(s | ((d & 127) << 20)), __expf(a));
        recB[pos] = s2;
    }
}

// ---- layer-1 LDS-push aggregation + fused finalize -> h1 ----
__global__ __launch_bounds__(256) void k_agg1(
    const int* __restrict__ scanned, const float2* __restrict__ recA,
    const __half* __restrict__ hx, const float* __restrict__ aS,
    const float* __restrict__ aD, const float* __restrict__ bias,
    float* __restrict__ h1, int n_nodes)
{
    __shared__ float acc[128 * 64];
    __shared__ float den[128];
    int tid = threadIdx.x, bk = blockIdx.x;
    for (int j = tid; j < 128 * 64; j += 256) acc[j] = 0.f;
    if (tid < 128) den[tid] = 0.f;
    __syncthreads();
    int start = scanned[bk * NBLK];
    int end = scanned[(bk + 1) * NBLK];  // bk==NBK-1 -> sentinel == E
    int wv = tid >> 6, lane = tid & 63;
    for (int base = start + wv * 64; base < end; base += 256) {
        int cnt = min(end - base, 64);
        int bits = 0; float ex = 0.f;
        if (lane < cnt) {
            float2 r = recA[base + lane];
            bits = __float_as_int(r.x); ex = r.y;
            atomicAdd(&den[bits >> 20], ex);   // one den add per record, by owning lane
        }
        int j = 0;
        for (; j + 4 <= cnt; j += 4) {
            int b0 = __shfl(bits, j), b1 = __shfl(bits, j + 1), b2 = __shfl(bits, j + 2), b3 = __shfl(bits, j + 3);
            float e0 = __shfl(ex, j), e1 = __shfl(ex, j + 1), e2 = __shfl(ex, j + 2), e3 = __shfl(ex, j + 3);
            float h0 = __half2float(hx[(size_t)(b0 & SMASK) * 64 + lane]);
            float h1v = __half2float(hx[(size_t)(b1 & SMASK) * 64 + lane]);
            float h2v = __half2float(hx[(size_t)(b2 & SMASK) * 64 + lane]);
            float h3v = __half2float(hx[(size_t)(b3 & SMASK) * 64 + lane]);
            atomicAdd(&acc[(b0 >> 20) * 64 + lane], e0 * h0);
            atomicAdd(&acc[(b1 >> 20) * 64 + lane], e1 * h1v);
            atomicAdd(&acc[(b2 >> 20) * 64 + lane], e2 * h2v);
            atomicAdd(&acc[(b3 >> 20) * 64 + lane], e3 * h3v);
        }
        for (; j < cnt; ++j) {
            int bj = __shfl(bits, j); float ej = __shfl(ex, j);
            atomicAdd(&acc[(bj >> 20) * 64 + lane], ej * __half2float(hx[(size_t)(bj & SMASK) * 64 + lane]));
        }
    }
    __syncthreads();
    int n0 = bk << 7;
    for (int dl = wv; dl < 128; dl += 4) {
        int n = n0 + dl;
        if (n >= n_nodes) break;
        float al = aS[n] + aD[n];
        al = al > 0.f ? al : 0.2f * al;
        float exl = __expf(al);
        float hself = __half2float(hx[(size_t)n * 64 + lane]);
        float val = (acc[dl * 64 + lane] + exl * hself) / (den[dl] + exl) + bias[lane];
        h1[(size_t)n * 64 + lane] = val > 0.f ? val : expm1f(val);
    }
}

// ---- layer-2 node transform: hx2 = h1 @ W2 (64->32), alpha_s/d ----
__global__ __launch_bounds__(256) void k_node2(
    const float* __restrict__ h1, const float* __restrict__ W,
    const float* __restrict__ a_s, const float* __restrict__ a_d,
    float* __restrict__ hx, float* __restrict__ aS, float* __restrict__ aD, int n_nodes)
{
    __shared__ float Wl[64 * 32];
    __shared__ float xs[8][64];
    int tid = threadIdx.x;
#pragma unroll
    for (int i = 0; i < 8; ++i) Wl[tid + i * 256] = W[tid + i * 256];
    int n0 = blockIdx.x * 8;
    for (int i = tid; i < 8 * 64; i += 256) {
        int r = i >> 6;
        int n = n0 + r;
        xs[r][i & 63] = (n < n_nodes) ? h1[(size_t)n * 64 + (i & 63)] : 0.f;
    }
    __syncthreads();
    int g = tid >> 5, c = tid & 31;
    int n = n0 + g;
    if (n >= n_nodes) return;
    float h = 0.f;
#pragma unroll
    for (int k = 0; k < 64; ++k) h += xs[g][k] * Wl[k * 32 + c];
    hx[(size_t)n * 32 + c] = h;
    float ps = h * a_s[c], pd = h * a_d[c];
#pragma unroll
    for (int o = 16; o > 0; o >>= 1) { ps += __shfl_xor(ps, o, 32); pd += __shfl_xor(pd, o, 32); }
    if (c == 0) { aS[n] = ps; aD[n] = pd; }
}

// ---- layer-2 LDS-push aggregation (mask-filtered records) -> out2 per node ----
__global__ __launch_bounds__(256) void k_agg2(
    const int* __restrict__ scanned, const float2* __restrict__ recA,
    const float* __restrict__ recB, const float* __restrict__ hx,
    const float* __restrict__ aS, const float* __restrict__ aD,
    const int* __restrict__ msk, const float* __restrict__ bias,
    float* __restrict__ out2, int n_nodes)
{
    __shared__ float acc[128 * 32];
    __shared__ float den[128];
    __shared__ int mloc[128];
    int tid = threadIdx.x, bk = blockIdx.x;
    int n0 = bk << 7;
    for (int j = tid; j < 128 * 32; j += 256) acc[j] = 0.f;
    if (tid < 128) {
        den[tid] = 0.f;
        int n = n0 + tid;
        mloc[tid] = (n < n_nodes) ? msk[n] : 0;
    }
    __syncthreads();
    int start = scanned[bk * NBLK];
    int end = scanned[(bk + 1) * NBLK];
    int wv = tid >> 6, lane = tid & 63;
    int half = lane >> 5, c = lane & 31;
    for (int base = start + wv * 64; base < end; base += 256) {
        int cnt = min(end - base, 64);
        int bits = 0; float ex = 0.f; int keep = 0;
        if (lane < cnt) {
            float2 r = recA[base + lane];
            bits = __float_as_int(r.x);
            keep = mloc[bits >> 20];
            if (keep) {
                float ae2 = recB[base + lane];
                float a = aS[bits & SMASK] + aD[n0 + (bits >> 20)] + ae2;
                a = a > 0.f ? a : 0.2f * a;
                ex = __expf(a);
                atomicAdd(&den[bits >> 20], ex);
            }
        }
        for (int j = 0; j < cnt; j += 2) {   // 32 lanes per record, 2 records at once
            int jj = j + half;
            int bj = __shfl(bits, jj); float ej = __shfl(ex, jj); int kj = __shfl(keep, jj);
            if (jj < cnt && kj) {
                atomicAdd(&acc[(bj >> 20) * 32 + c], ej * hx[(size_t)(bj & SMASK) * 32 + c]);
            }
        }
    }
    __syncthreads();
    for (int dl = tid >> 5; dl < 128; dl += 8) {
        int n = n0 + dl;
        if (n >= n_nodes) break;
        if (!mloc[dl]) continue;
        int cc = tid & 31;
        float al = aS[n] + aD[n];
        al = al > 0.f ? al : 0.2f * al;
        float exl = __expf(al);
        float val = (acc[dl * 32 + cc] + exl * hx[(size_t)n * 32 + cc]) / (den[dl] + exl) + bias[cc];
        out2[(size_t)n * 32 + cc] = val > 0.f ? val : expm1f(val);
    }
}

// ---- gather masked rows (handles duplicate mask entries) ----
__global__ __launch_bounds__(256) void k_out(const int* __restrict__ mask,
                                             const float* __restrict__ out2,
                                             float* __restrict__ out, int m_cnt) {
    int i = blockIdx.x * 256 + threadIdx.x;
    int m = i >> 5, c = i & 31;
    if (m < m_cnt) out[(size_t)m * 32 + c] = out2[(size_t)mask[m] * 32 + c];
}

extern "C" void kernel_launch(void* const* d_in, const int* in_sizes, int n_in,
                              void* d_out, int out_size, void* d_ws, size_t ws_size,
                              hipStream_t stream) {
    const float* x    = (const float*)d_in[0];
    const int*   ei   = (const int*)d_in[1];
    const int*   mask = (const int*)d_in[2];
    const float* ea   = (const float*)d_in[3];
    const float* W1   = (const float*)d_in[4];
    const float* a_s1 = (const float*)d_in[5];
    const float* a_d1 = (const float*)d_in[6];
    const float* We1  = (const float*)d_in[7];
    const float* a_e1 = (const float*)d_in[8];
    const float* b1   = (const float*)d_in[9];
    const float* W2   = (const float*)d_in[10];
    const float* a_s2 = (const float*)d_in[11];
    const float* a_d2 = (const float*)d_in[12];
    const float* We2  = (const float*)d_in[13];
    const float* a_e2 = (const float*)d_in[14];
    const float* b2   = (const float*)d_in[15];
    const int* src = ei;
    const int* dst = ei + EE;
    float* out = (float*)d_out;

    char* w = (char*)d_ws;
    size_t off = 0;
    auto take = [&](size_t bytes) -> char* {
        char* p = w + off;
        off += (bytes + 255) & ~(size_t)255;
        return p;
    };
    float*  v1      = (float*)take(16 * 4);
    float*  v2      = (float*)take(16 * 4);
    __half* hx1h    = (__half*)take((size_t)NN * 64 * 2);
    float*  aS1     = (float*)take((size_t)NN * 4);
    float*  aD1     = (float*)take((size_t)NN * 4);
    float*  h1      = (float*)take((size_t)NN * 64 * 4);
    float*  hx2     = (float*)take((size_t)NN * 32 * 4);
    float*  aS2     = (float*)take((size_t)NN * 4);
    float*  aD2     = (float*)take((size_t)NN * 4);
    float*  out2    = (float*)take((size_t)NN * 32 * 4);
    int*    msk     = (int*)take((size_t)NN * 4);
    int*    hist    = (int*)take((size_t)N_SCAN * 4);
    int*    scanned = (int*)take((size_t)N_SCAN * 4);
    int*    bsum    = (int*)take(256 * 4);
    float2* recA    = (float2*)take((size_t)EE * 8);
    float*  recB    = (float*)take((size_t)EE * 4);

    const int nscan_blocks = (N_SCAN + 2047) / 2048;  // 100

    k_v<<<1, 64, 0, stream>>>(We1, a_e1, We2, a_e2, v1, v2);
    k_node1<<<(NN + 3) / 4, 256, 0, stream>>>(x, W1, a_s1, a_d1, hx1h, aS1, aD1, msk, NN);
    k_mask<<<(MM + 255) / 256, 256, 0, stream>>>(mask, msk, MM);
    k_bhist<<<NBLK, 256, 0, stream>>>(dst, hist, EE);
    k_scan1<<<nscan_blocks, 256, 0, stream>>>(hist, scanned, bsum, N_SCAN);
    k_scan2<<<1, 256, 0, stream>>>(bsum, nscan_blocks);
    k_scan3<<<(N_SCAN + 255) / 256, 256, 0, stream>>>(scanned, bsum, N_SCAN);
    k_scatter<<<NBLK, 256, 0, stream>>>(ea, v1, v2, src, dst, aS1, aD1, scanned, recA, recB, EE);
    k_agg1<<<NBK, 256, 0, stream>>>(scanned, recA, hx1h, aS1, aD1, b1, h1, NN);
    k_node2<<<(NN + 7) / 8, 256, 0, stream>>>(h1, W2, a_s2, a_d2, hx2, aS2, aD2, NN);
    k_agg2<<<NBK, 256, 0, stream>>>(scanned, recA, recB, hx2, aS2, aD2, msk, b2, out2, NN);
    k_out<<<(MM * 32 + 255) / 256, 256, 0, stream>>>(mask, out2, out, MM);
}

// Round 7
// 367.378 us; speedup vs baseline: 2.8945x; 2.8945x over previous
//
#include <hip/hip_runtime.h>
#include <hip/hip_bf16.h>
#include <hip/hip_fp16.h>
#include <math.h>

#define NN 100000
#define EE 1600000
#define MM 20000
#define EPB 6144                        // edges per partition block (multiple of 256)
#define NBLK ((EE + EPB - 1) / EPB)     // 261 partition blocks
#define NBK8 8                          // 8 coarse dst buckets (1 per XCD)
#define BWID 12500                      // nodes per bucket (8*12500 = 100000 exactly)
#define N_SCAN8 (NBK8 * NBLK + 1)       // 2089 (+ sentinel)
#define SMASK 0x1FFFF                   // low 17 bits: src id
#define SPLITS 128                      // k_place splits per bucket

// ---- tiny: v1[16] = We1 @ a_e1 (64), v2[16] = We2 @ a_e2 (32) ----
__global__ void k_v(const float* __restrict__ We1, const float* __restrict__ ae1v,
                    const float* __restrict__ We2, const float* __restrict__ ae2v,
                    float* __restrict__ v1, float* __restrict__ v2) {
    int t = threadIdx.x;
    if (t < 16) {
        float s = 0.f;
        for (int c = 0; c < 64; ++c) s += We1[t * 64 + c] * ae1v[c];
        v1[t] = s;
    } else if (t < 32) {
        int r = t - 16;
        float s = 0.f;
        for (int c = 0; c < 32; ++c) s += We2[r * 32 + c] * ae2v[c];
        v2[r] = s;
    }
}

// ---- layer-1 node transform: hx1 (fp16) = x @ W1, alpha_s/d; zero deg ----
__global__ __launch_bounds__(256) void k_node1(
    const float* __restrict__ x, const float* __restrict__ W,
    const float* __restrict__ a_s, const float* __restrict__ a_d,
    __half* __restrict__ hx, float* __restrict__ aS, float* __restrict__ aD,
    int* __restrict__ deg, int n_nodes)
{
    __shared__ float Wl[64 * 64];
    __shared__ float xs[4][64];
    int tid = threadIdx.x;
#pragma unroll
    for (int i = 0; i < 16; ++i) Wl[tid + i * 256] = W[tid + i * 256];
    int wv = tid >> 6, lane = tid & 63;
    int n = blockIdx.x * 4 + wv;
    bool act = (n < n_nodes);
    if (act) xs[wv][lane] = x[(size_t)n * 64 + lane];
    __syncthreads();
    if (!act) return;
    float h = 0.f;
#pragma unroll
    for (int k = 0; k < 64; ++k) h += xs[wv][k] * Wl[k * 64 + lane];
    hx[(size_t)n * 64 + lane] = __float2half(h);
    float ps = h * a_s[lane];
    float pd = h * a_d[lane];
#pragma unroll
    for (int o = 32; o > 0; o >>= 1) { ps += __shfl_xor(ps, o); pd += __shfl_xor(pd, o); }
    if (lane == 0) { aS[n] = ps; aD[n] = pd; deg[n] = 0; }
}

// ---- dst-degree histogram + per-(bucket,block) coarse histogram ----
__global__ __launch_bounds__(256) void k_deg(const int* __restrict__ dst,
                                             int* __restrict__ deg,
                                             int* __restrict__ bh, int E) {
    __shared__ int h8[8];
    int tid = threadIdx.x, blk = blockIdx.x, lane = tid & 63;
    if (tid < 8) h8[tid] = 0;
    __syncthreads();
    int e0 = blk * EPB, e1 = min(E, e0 + EPB);
    for (int e = e0 + tid; e < e1; e += 256) {
        int d = dst[e];
        atomicAdd(&deg[d], 1);
        int b = d / BWID;
#pragma unroll
        for (int bk = 0; bk < 8; ++bk) {
            unsigned long long m = __ballot(b == bk);
            if (b == bk && __popcll(m & ((1ull << lane) - 1)) == 0)
                atomicAdd(&h8[bk], (int)__popcll(m));
        }
    }
    __syncthreads();
    if (tid < 8) bh[tid * NBLK + blk] = h8[tid];
    if (blk == 0 && tid == 0) bh[NBK8 * NBLK] = 0;   // sentinel -> scan total
}

// ---- scan kernels: exclusive prefix (2048 elems/block) ----
__global__ __launch_bounds__(256) void k_scan1(const int* __restrict__ deg, int* __restrict__ pre,
                                               int* __restrict__ bsum, int n) {
    __shared__ int wsum[4];
    int t = threadIdx.x;
    int base = blockIdx.x * 2048 + t * 8;
    int v[8]; int s = 0;
#pragma unroll
    for (int i = 0; i < 8; ++i) { int idx = base + i; int d = (idx < n) ? deg[idx] : 0; v[i] = s; s += d; }
    int lane = t & 63, wv = t >> 6;
    int incl = s;
#pragma unroll
    for (int off = 1; off < 64; off <<= 1) { int y = __shfl_up(incl, off); if (lane >= off) incl += y; }
    if (lane == 63) wsum[wv] = incl;
    __syncthreads();
    int woff = 0;
    for (int w = 0; w < wv; ++w) woff += wsum[w];
    int texcl = woff + incl - s;
#pragma unroll
    for (int i = 0; i < 8; ++i) { int idx = base + i; if (idx < n) pre[idx] = texcl + v[i]; }
    if (t == 255) bsum[blockIdx.x] = woff + incl;
}

__global__ __launch_bounds__(256) void k_scan2(int* __restrict__ bsum, int nb) {
    __shared__ int ws[4];
    int t = threadIdx.x, lane = t & 63, wv = t >> 6;
    int x = (t < nb) ? bsum[t] : 0;
    int incl = x;
#pragma unroll
    for (int off = 1; off < 64; off <<= 1) { int y = __shfl_up(incl, off); if (lane >= off) incl += y; }
    if (lane == 63) ws[wv] = incl;
    __syncthreads();
    int woff = 0;
    for (int w = 0; w < wv; ++w) woff += ws[w];
    if (t < nb) bsum[t] = woff + incl - x;
}

__global__ void k_scan3(int* __restrict__ pre, const int* __restrict__ bsum,
                        int* __restrict__ cur, int n) {
    int i = blockIdx.x * 256 + threadIdx.x;
    if (i < n) { int r = pre[i] + bsum[i >> 11]; pre[i] = r; cur[i] = r; }
}

__global__ void k_scan3b(int* __restrict__ pre, const int* __restrict__ bsum, int n) {
    int i = blockIdx.x * 256 + threadIdx.x;
    if (i < n) pre[i] += bsum[i >> 11];
}

// ---- pass 1: edge dots + exp(alpha1); ballot-coalesced scatter into 8 coarse
//      dst buckets, block-owned segments (contiguous runs -> full-line writes) ----
__global__ __launch_bounds__(256) void k_part(
    const float* __restrict__ ea, const float* __restrict__ v1, const float* __restrict__ v2,
    const int* __restrict__ src, const int* __restrict__ dst,
    const float* __restrict__ aS1, const float* __restrict__ aD1,
    const int* __restrict__ scanned8, uint2* __restrict__ recMid, int E)
{
    __shared__ int lcur[8];
    int tid = threadIdx.x, blk = blockIdx.x, lane = tid & 63;
    if (tid < 8) lcur[tid] = scanned8[tid * NBLK + blk];
    __syncthreads();
    int e0 = blk * EPB, e1 = min(E, e0 + EPB);
    for (int e = e0 + tid; e < e1; e += 256) {
        const float* p = ea + (size_t)e * 16;
        float s1 = 0.f, s2 = 0.f;
#pragma unroll
        for (int i = 0; i < 16; ++i) { float t = p[i]; s1 += t * v1[i]; s2 += t * v2[i]; }
        int s = src[e], d = dst[e];
        float a = aS1[s] + aD1[d] + s1;
        a = a > 0.f ? a : 0.2f * a;
        float ex = __expf(a);
        int b = d / BWID;
        int dloc = d - b * BWID;                      // < 12500, 14 bits
        unsigned lo = (unsigned)s | ((unsigned)dloc << 17);
        unsigned hi = (unsigned)__half_as_ushort(__float2half(ex))
                    | ((unsigned)__half_as_ushort(__float2half(s2)) << 16);
        int pos = 0;
#pragma unroll
        for (int bk = 0; bk < 8; ++bk) {
            unsigned long long m = __ballot(b == bk);
            if (b == bk) {
                int leader = __ffsll((unsigned long long)m) - 1;
                int rank = (int)__popcll(m & ((1ull << lane) - 1));
                int base = 0;
                if (lane == leader) base = atomicAdd(&lcur[bk], (int)__popcll(m));
                base = __shfl(base, leader);
                pos = base + rank;
            }
        }
        recMid[pos] = make_uint2(lo, hi);
    }
}

// ---- pass 2: exact CSR placement within XCD-pinned 1.6MB bucket window ----
__global__ __launch_bounds__(256) void k_place(
    const int* __restrict__ scanned8, const uint2* __restrict__ recMid,
    int* __restrict__ cur, uint2* __restrict__ rec, int E)
{
    int bid = blockIdx.x;
    int b = bid & 7, s = bid >> 3;                    // bid%8==bucket -> same XCD
    int B0 = scanned8[b * NBLK];
    int B1 = scanned8[(b + 1) * NBLK];                // b==7 hits sentinel == E
    int len = B1 - B0;
    int lo = B0 + (int)((long long)len * s / SPLITS);
    int hi = B0 + (int)((long long)len * (s + 1) / SPLITS);
    int dbase = b * BWID;
    for (int i = lo + (int)threadIdx.x; i < hi; i += 256) {
        uint2 r = recMid[i];
        int d = dbase + (int)(r.x >> 17);
        int p = atomicAdd(&cur[d], 1);
        rec[p] = r;
    }
}

// ---- layer-1 pull aggregation + finalize (self-loop, div, bias, elu) -> h1 ----
__global__ __launch_bounds__(256) void k_agg1(
    const int* __restrict__ rowptr, const int* __restrict__ rowend,
    const uint2* __restrict__ rec, const __half* __restrict__ hx,
    const float* __restrict__ aS, const float* __restrict__ aD,
    const float* __restrict__ b, float* __restrict__ h1)
{
    int wv = threadIdx.x >> 6, lane = threadIdx.x & 63;
    int bid = blockIdx.x;
    int n = (bid & 7) * BWID + (bid >> 3) * 4 + wv;   // bucket-aligned for L2-local rec reads
    int start = rowptr[n], end = rowend[n];
    float r = 0.f, den = 0.f;
    for (int base = start; base < end; base += 64) {
        int cnt = min(end - base, 64);
        int s = 0; float ex = 0.f;
        if (lane < cnt) {
            uint2 R = rec[base + lane];
            s = (int)(R.x & SMASK);
            ex = __half2float(__ushort_as_half((unsigned short)(R.y & 0xFFFFu)));
        }
        int j = 0;
        for (; j + 4 <= cnt; j += 4) {
            int s0 = __shfl(s, j), s1 = __shfl(s, j + 1), s2 = __shfl(s, j + 2), s3 = __shfl(s, j + 3);
            float e0 = __shfl(ex, j), e1 = __shfl(ex, j + 1), e2 = __shfl(ex, j + 2), e3 = __shfl(ex, j + 3);
            float h0 = __half2float(hx[(size_t)s0 * 64 + lane]);
            float h1v = __half2float(hx[(size_t)s1 * 64 + lane]);
            float h2 = __half2float(hx[(size_t)s2 * 64 + lane]);
            float h3 = __half2float(hx[(size_t)s3 * 64 + lane]);
            r += e0 * h0; r += e1 * h1v; r += e2 * h2; r += e3 * h3;
            den += e0 + e1 + e2 + e3;
        }
        for (; j < cnt; ++j) {
            int sj = __shfl(s, j); float ej = __shfl(ex, j);
            r += ej * __half2float(hx[(size_t)sj * 64 + lane]);
            den += ej;
        }
    }
    float al = aS[n] + aD[n];
    al = al > 0.f ? al : 0.2f * al;
    float exl = __expf(al);
    float hself = __half2float(hx[(size_t)n * 64 + lane]);
    float val = (r + exl * hself) / (den + exl) + b[lane];
    h1[(size_t)n * 64 + lane] = val > 0.f ? val : expm1f(val);
}

// ---- layer-2 node transform: hx2 = h1 @ W2 (64->32), alpha_s/d ----
__global__ __launch_bounds__(256) void k_node2(
    const float* __restrict__ h1, const float* __restrict__ W,
    const float* __restrict__ a_s, const float* __restrict__ a_d,
    float* __restrict__ hx, float* __restrict__ aS, float* __restrict__ aD, int n_nodes)
{
    __shared__ float Wl[64 * 32];
    __shared__ float xs[8][64];
    int tid = threadIdx.x;
#pragma unroll
    for (int i = 0; i < 8; ++i) Wl[tid + i * 256] = W[tid + i * 256];
    int n0 = blockIdx.x * 8;
    for (int i = tid; i < 8 * 64; i += 256) {
        int r = i >> 6;
        int n = n0 + r;
        xs[r][i & 63] = (n < n_nodes) ? h1[(size_t)n * 64 + (i & 63)] : 0.f;
    }
    __syncthreads();
    int g = tid >> 5, c = tid & 31;
    int n = n0 + g;
    if (n >= n_nodes) return;
    float h = 0.f;
#pragma unroll
    for (int k = 0; k < 64; ++k) h += xs[g][k] * Wl[k * 32 + c];
    hx[(size_t)n * 32 + c] = h;
    float ps = h * a_s[c], pd = h * a_d[c];
#pragma unroll
    for (int o = 16; o > 0; o >>= 1) { ps += __shfl_xor(ps, o, 32); pd += __shfl_xor(pd, o, 32); }
    if (c == 0) { aS[n] = ps; aD[n] = pd; }
}

// ---- layer-2 pull aggregation over masked nodes only + finalize -> out ----
__global__ __launch_bounds__(256) void k_agg2(
    const int* __restrict__ mask,
    const int* __restrict__ rowptr, const int* __restrict__ rowend,
    const uint2* __restrict__ rec, const float* __restrict__ hx,
    const float* __restrict__ aS, const float* __restrict__ aD,
    const float* __restrict__ b, float* __restrict__ out, int m_cnt)
{
    int wv = threadIdx.x >> 6, lane = threadIdx.x & 63;
    int m = blockIdx.x * 4 + wv;
    if (m >= m_cnt) return;
    int n = mask[m];
    int start = rowptr[n], end = rowend[n];
    float aDn = aD[n];
    int half = lane >> 5, c = lane & 31;
    float r = 0.f, den = 0.f;
    for (int base = start; base < end; base += 64) {
        int cnt = min(end - base, 64);
        int s = 0; float ex = 0.f;
        if (lane < cnt) {
            uint2 R = rec[base + lane];
            s = (int)(R.x & SMASK);
            float ae2 = __half2float(__ushort_as_half((unsigned short)(R.y >> 16)));
            float a = aS[s] + aDn + ae2;
            a = a > 0.f ? a : 0.2f * a;
            ex = __expf(a);
        }
        int j = 0;
        for (; j + 8 <= cnt; j += 8) {
            int j0 = j + half, j2 = j + 2 + half, j4 = j + 4 + half, j6 = j + 6 + half;
            int s0 = __shfl(s, j0), s2v = __shfl(s, j2), s4 = __shfl(s, j4), s6 = __shfl(s, j6);
            float e0 = __shfl(ex, j0), e2 = __shfl(ex, j2), e4 = __shfl(ex, j4), e6 = __shfl(ex, j6);
            r += e0 * hx[(size_t)s0 * 32 + c];
            r += e2 * hx[(size_t)s2v * 32 + c];
            r += e4 * hx[(size_t)s4 * 32 + c];
            r += e6 * hx[(size_t)s6 * 32 + c];
            den += e0 + e2 + e4 + e6;
        }
        for (; j < cnt; j += 2) {
            int jj = j + half;
            if (jj < cnt) {
                int sj = __shfl(s, jj); float ej = __shfl(ex, jj);
                r += ej * hx[(size_t)sj * 32 + c];
                den += ej;
            }
        }
    }
    float ro = __shfl(r, lane ^ 32);
    float do_ = __shfl(den, lane ^ 32);
    r += ro; den += do_;
    if (half == 0) {
        float al = aS[n] + aDn;
        al = al > 0.f ? al : 0.2f * al;
        float exl = __expf(al);
        float val = (r + exl * hx[(size_t)n * 32 + c]) / (den + exl) + b[c];
        out[(size_t)m * 32 + c] = val > 0.f ? val : expm1f(val);
    }
}

extern "C" void kernel_launch(void* const* d_in, const int* in_sizes, int n_in,
                              void* d_out, int out_size, void* d_ws, size_t ws_size,
                              hipStream_t stream) {
    const float* x    = (const float*)d_in[0];
    const int*   ei   = (const int*)d_in[1];
    const int*   mask = (const int*)d_in[2];
    const float* ea   = (const float*)d_in[3];
    const float* W1   = (const float*)d_in[4];
    const float* a_s1 = (const float*)d_in[5];
    const float* a_d1 = (const float*)d_in[6];
    const float* We1  = (const float*)d_in[7];
    const float* a_e1 = (const float*)d_in[8];
    const float* b1   = (const float*)d_in[9];
    const float* W2   = (const float*)d_in[10];
    const float* a_s2 = (const float*)d_in[11];
    const float* a_d2 = (const float*)d_in[12];
    const float* We2  = (const float*)d_in[13];
    const float* a_e2 = (const float*)d_in[14];
    const float* b2   = (const float*)d_in[15];
    const int* src = ei;
    const int* dst = ei + EE;
    float* out = (float*)d_out;

    char* w = (char*)d_ws;
    size_t off = 0;
    auto take = [&](size_t bytes) -> char* {
        char* p = w + off;
        off += (bytes + 255) & ~(size_t)255;
        return p;
    };
    float*  v1       = (float*)take(16 * 4);
    float*  v2       = (float*)take(16 * 4);
    __half* hx1h     = (__half*)take((size_t)NN * 64 * 2);
    float*  aS1      = (float*)take((size_t)NN * 4);
    float*  aD1      = (float*)take((size_t)NN * 4);
    float*  h1       = (float*)take((size_t)NN * 64 * 4);
    float*  hx2      = (float*)take((size_t)NN * 32 * 4);
    float*  aS2      = (float*)take((size_t)NN * 4);
    float*  aD2      = (float*)take((size_t)NN * 4);
    int*    deg      = (int*)take((size_t)NN * 4);
    int*    rowptr   = (int*)take((size_t)NN * 4);
    int*    cur      = (int*)take((size_t)NN * 4);
    int*    bh       = (int*)take((size_t)N_SCAN8 * 4);
    int*    scanned8 = (int*)take((size_t)N_SCAN8 * 4);
    int*    bsum     = (int*)take(256 * 4);
    uint2*  recMid   = (uint2*)take((size_t)EE * 8);
    uint2*  rec      = (uint2*)take((size_t)EE * 8);

    const int nb_deg = (NN + 2047) / 2048;        // 49
    const int nb_bh  = (N_SCAN8 + 2047) / 2048;   // 2

    k_v<<<1, 64, 0, stream>>>(We1, a_e1, We2, a_e2, v1, v2);
    k_node1<<<(NN + 3) / 4, 256, 0, stream>>>(x, W1, a_s1, a_d1, hx1h, aS1, aD1, deg, NN);
    k_deg<<<NBLK, 256, 0, stream>>>(dst, deg, bh, EE);
    // scan deg -> rowptr (+cur copy)
    k_scan1<<<nb_deg, 256, 0, stream>>>(deg, rowptr, bsum, NN);
    k_scan2<<<1, 256, 0, stream>>>(bsum, nb_deg);
    k_scan3<<<(NN + 255) / 256, 256, 0, stream>>>(rowptr, bsum, cur, NN);
    // scan bh -> scanned8 (per-(bucket,block) segment bases)
    k_scan1<<<nb_bh, 256, 0, stream>>>(bh, scanned8, bsum, N_SCAN8);
    k_scan2<<<1, 256, 0, stream>>>(bsum, nb_bh);
    k_scan3b<<<(N_SCAN8 + 255) / 256, 256, 0, stream>>>(scanned8, bsum, N_SCAN8);
    // two-level partition
    k_part<<<NBLK, 256, 0, stream>>>(ea, v1, v2, src, dst, aS1, aD1, scanned8, recMid, EE);
    k_place<<<8 * SPLITS, 256, 0, stream>>>(scanned8, recMid, cur, rec, EE);
    // aggregation + layer 2
    k_agg1<<<8 * (BWID / 4), 256, 0, stream>>>(rowptr, cur, rec, hx1h, aS1, aD1, b1, h1);
    k_node2<<<(NN + 7) / 8, 256, 0, stream>>>(h1, W2, a_s2, a_d2, hx2, aS2, aD2, NN);
    k_agg2<<<(MM + 3) / 4, 256, 0, stream>>>(mask, rowptr, cur, rec, hx2, aS2, aD2, b2, out, MM);
}

// Round 8
// 349.888 us; speedup vs baseline: 3.0392x; 1.0500x over previous
//
#include <hip/hip_runtime.h>
#include <hip/hip_bf16.h>
#include <hip/hip_fp16.h>
#include <math.h>

#define NN 100000
#define EE 1600000
#define MM 20000
#define EPB 1536                        // edges per partition block (multiple of 256)
#define NBLK ((EE + EPB - 1) / EPB)     // 1042 partition blocks
#define NBK8 8                          // 8 coarse dst buckets (1 per XCD)
#define BWID 12500                      // nodes per bucket (8*12500 = 100000 exactly)
#define N_SCAN8 (NBK8 * NBLK + 1)       // 8337 (+ sentinel)
#define SMASK 0x1FFFF                   // low 17 bits: src id
#define SPLITS 256                      // k_place splits per bucket

// ---- tiny: v1[16] = We1 @ a_e1 (64), v2[16] = We2 @ a_e2 (32) ----
__global__ void k_v(const float* __restrict__ We1, const float* __restrict__ ae1v,
                    const float* __restrict__ We2, const float* __restrict__ ae2v,
                    float* __restrict__ v1, float* __restrict__ v2) {
    int t = threadIdx.x;
    if (t < 16) {
        float s = 0.f;
        for (int c = 0; c < 64; ++c) s += We1[t * 64 + c] * ae1v[c];
        v1[t] = s;
    } else if (t < 32) {
        int r = t - 16;
        float s = 0.f;
        for (int c = 0; c < 32; ++c) s += We2[r * 32 + c] * ae2v[c];
        v2[r] = s;
    }
}

// ---- layer-1 node transform: hx1 (fp16) = x @ W1, alpha_s/d; zero deg ----
__global__ __launch_bounds__(256) void k_node1(
    const float* __restrict__ x, const float* __restrict__ W,
    const float* __restrict__ a_s, const float* __restrict__ a_d,
    __half* __restrict__ hx, float* __restrict__ aS, float* __restrict__ aD,
    int* __restrict__ deg, int n_nodes)
{
    __shared__ float Wl[64 * 64];
    __shared__ float xs[4][64];
    int tid = threadIdx.x;
#pragma unroll
    for (int i = 0; i < 16; ++i) Wl[tid + i * 256] = W[tid + i * 256];
    int wv = tid >> 6, lane = tid & 63;
    int n = blockIdx.x * 4 + wv;
    bool act = (n < n_nodes);
    if (act) xs[wv][lane] = x[(size_t)n * 64 + lane];
    __syncthreads();
    if (!act) return;
    float h = 0.f;
#pragma unroll
    for (int k = 0; k < 64; ++k) h += xs[wv][k] * Wl[k * 64 + lane];
    hx[(size_t)n * 64 + lane] = __float2half(h);
    float ps = h * a_s[lane];
    float pd = h * a_d[lane];
#pragma unroll
    for (int o = 32; o > 0; o >>= 1) { ps += __shfl_xor(ps, o); pd += __shfl_xor(pd, o); }
    if (lane == 0) { aS[n] = ps; aD[n] = pd; deg[n] = 0; }
}

// ---- dst-degree histogram + per-(bucket,block) coarse histogram ----
__global__ __launch_bounds__(256) void k_deg(const int* __restrict__ dst,
                                             int* __restrict__ deg,
                                             int* __restrict__ bh, int E) {
    __shared__ int h8[8];
    int tid = threadIdx.x, blk = blockIdx.x, lane = tid & 63;
    if (tid < 8) h8[tid] = 0;
    __syncthreads();
    int e0 = blk * EPB, e1 = min(E, e0 + EPB);
    int c[8] = {0, 0, 0, 0, 0, 0, 0, 0};
    for (int e = e0 + tid; e < e1; e += 256) {
        int d = dst[e];
        atomicAdd(&deg[d], 1);
        int b = d / BWID;
#pragma unroll
        for (int bk = 0; bk < 8; ++bk) c[bk] += (b == bk);
    }
#pragma unroll
    for (int bk = 0; bk < 8; ++bk) {
#pragma unroll
        for (int o = 32; o > 0; o >>= 1) c[bk] += __shfl_xor(c[bk], o);
        if (lane == 0 && c[bk]) atomicAdd(&h8[bk], c[bk]);
    }
    __syncthreads();
    if (tid < 8) bh[tid * NBLK + blk] = h8[tid];
    if (blk == 0 && tid == 0) bh[NBK8 * NBLK] = 0;   // sentinel -> scan total
}

// ---- scan kernels: exclusive prefix (2048 elems/block) ----
__global__ __launch_bounds__(256) void k_scan1(const int* __restrict__ deg, int* __restrict__ pre,
                                               int* __restrict__ bsum, int n) {
    __shared__ int wsum[4];
    int t = threadIdx.x;
    int base = blockIdx.x * 2048 + t * 8;
    int v[8]; int s = 0;
#pragma unroll
    for (int i = 0; i < 8; ++i) { int idx = base + i; int d = (idx < n) ? deg[idx] : 0; v[i] = s; s += d; }
    int lane = t & 63, wv = t >> 6;
    int incl = s;
#pragma unroll
    for (int off = 1; off < 64; off <<= 1) { int y = __shfl_up(incl, off); if (lane >= off) incl += y; }
    if (lane == 63) wsum[wv] = incl;
    __syncthreads();
    int woff = 0;
    for (int w = 0; w < wv; ++w) woff += wsum[w];
    int texcl = woff + incl - s;
#pragma unroll
    for (int i = 0; i < 8; ++i) { int idx = base + i; if (idx < n) pre[idx] = texcl + v[i]; }
    if (t == 255) bsum[blockIdx.x] = woff + incl;
}

__global__ __launch_bounds__(256) void k_scan2(int* __restrict__ bsum, int nb) {
    __shared__ int ws[4];
    int t = threadIdx.x, lane = t & 63, wv = t >> 6;
    int x = (t < nb) ? bsum[t] : 0;
    int incl = x;
#pragma unroll
    for (int off = 1; off < 64; off <<= 1) { int y = __shfl_up(incl, off); if (lane >= off) incl += y; }
    if (lane == 63) ws[wv] = incl;
    __syncthreads();
    int woff = 0;
    for (int w = 0; w < wv; ++w) woff += ws[w];
    if (t < nb) bsum[t] = woff + incl - x;
}

__global__ void k_scan3(int* __restrict__ pre, const int* __restrict__ bsum,
                        int* __restrict__ cur, int n) {
    int i = blockIdx.x * 256 + threadIdx.x;
    if (i < n) { int r = pre[i] + bsum[i >> 11]; pre[i] = r; cur[i] = r; }
}

__global__ void k_scan3b(int* __restrict__ pre, const int* __restrict__ bsum, int n) {
    int i = blockIdx.x * 256 + threadIdx.x;
    if (i < n) pre[i] += bsum[i >> 11];
}

// ---- pass 1: edge dots + exp(alpha1); ballot-coalesced scatter into 8 coarse
//      dst buckets, block-owned segments (contiguous runs -> full-line writes) ----
__global__ __launch_bounds__(256) void k_part(
    const float* __restrict__ ea, const float* __restrict__ v1, const float* __restrict__ v2,
    const int* __restrict__ src, const int* __restrict__ dst,
    const float* __restrict__ aS1, const float* __restrict__ aD1,
    const int* __restrict__ scanned8, uint2* __restrict__ recMid, int E)
{
    __shared__ int lcur[8];
    int tid = threadIdx.x, blk = blockIdx.x, lane = tid & 63;
    if (tid < 8) lcur[tid] = scanned8[tid * NBLK + blk];
    __syncthreads();
    const float4* v14 = (const float4*)v1;
    const float4* v24 = (const float4*)v2;
    float4 va0 = v14[0], va1 = v14[1], va2 = v14[2], va3 = v14[3];
    float4 vb0 = v24[0], vb1 = v24[1], vb2 = v24[2], vb3 = v24[3];
    int e0 = blk * EPB, e1 = min(E, e0 + EPB);
    for (int e = e0 + tid; e < e1; e += 256) {
        const float4* p4 = (const float4*)(ea + (size_t)e * 16);
        float4 q0 = p4[0], q1 = p4[1], q2 = p4[2], q3 = p4[3];
        float s1 = q0.x * va0.x + q0.y * va0.y + q0.z * va0.z + q0.w * va0.w
                 + q1.x * va1.x + q1.y * va1.y + q1.z * va1.z + q1.w * va1.w
                 + q2.x * va2.x + q2.y * va2.y + q2.z * va2.z + q2.w * va2.w
                 + q3.x * va3.x + q3.y * va3.y + q3.z * va3.z + q3.w * va3.w;
        float s2 = q0.x * vb0.x + q0.y * vb0.y + q0.z * vb0.z + q0.w * vb0.w
                 + q1.x * vb1.x + q1.y * vb1.y + q1.z * vb1.z + q1.w * vb1.w
                 + q2.x * vb2.x + q2.y * vb2.y + q2.z * vb2.z + q2.w * vb2.w
                 + q3.x * vb3.x + q3.y * vb3.y + q3.z * vb3.z + q3.w * vb3.w;
        int s = src[e], d = dst[e];
        float a = aS1[s] + aD1[d] + s1;
        a = a > 0.f ? a : 0.2f * a;
        float ex = __expf(a);
        int b = d / BWID;
        int dloc = d - b * BWID;                      // < 12500, 14 bits
        unsigned lo = (unsigned)s | ((unsigned)dloc << 17);
        unsigned hi = (unsigned)__half_as_ushort(__float2half(ex))
                    | ((unsigned)__half_as_ushort(__float2half(s2)) << 16);
        int pos = 0;
#pragma unroll
        for (int bk = 0; bk < 8; ++bk) {
            unsigned long long m = __ballot(b == bk);
            if (b == bk) {
                int leader = __ffsll((unsigned long long)m) - 1;
                int rank = (int)__popcll(m & ((1ull << lane) - 1));
                int base = 0;
                if (lane == leader) base = atomicAdd(&lcur[bk], (int)__popcll(m));
                base = __shfl(base, leader);
                pos = base + rank;
            }
        }
        recMid[pos] = make_uint2(lo, hi);
    }
}

// ---- pass 2: exact CSR placement within XCD-pinned 1.6MB bucket window ----
__global__ __launch_bounds__(256) void k_place(
    const int* __restrict__ scanned8, const uint2* __restrict__ recMid,
    int* __restrict__ cur, uint2* __restrict__ rec, int E)
{
    int bid = blockIdx.x;
    int b = bid & 7, s = bid >> 3;                    // bid%8==bucket -> same XCD
    int B0 = scanned8[b * NBLK];
    int B1 = scanned8[(b + 1) * NBLK];                // b==7 hits sentinel == E
    int len = B1 - B0;
    int lo = B0 + (int)((long long)len * s / SPLITS);
    int hi = B0 + (int)((long long)len * (s + 1) / SPLITS);
    int dbase = b * BWID;
    for (int i = lo + (int)threadIdx.x; i < hi; i += 256) {
        uint2 r = recMid[i];
        int d = dbase + (int)(r.x >> 17);
        int p = atomicAdd(&cur[d], 1);
        rec[p] = r;
    }
}

// ---- layer-1 pull aggregation + finalize (self-loop, div, bias, elu) -> h1 ----
__global__ __launch_bounds__(256) void k_agg1(
    const int* __restrict__ rowptr, const int* __restrict__ rowend,
    const uint2* __restrict__ rec, const __half* __restrict__ hx,
    const float* __restrict__ aS, const float* __restrict__ aD,
    const float* __restrict__ b, float* __restrict__ h1)
{
    int wv = threadIdx.x >> 6, lane = threadIdx.x & 63;
    int bid = blockIdx.x;
    int n = (bid & 7) * BWID + (bid >> 3) * 4 + wv;   // bucket-aligned for L2-local rec reads
    int start = rowptr[n], end = rowend[n];
    float r = 0.f, den = 0.f;
    for (int base = start; base < end; base += 64) {
        int cnt = min(end - base, 64);
        int s = 0; float ex = 0.f;
        if (lane < cnt) {
            uint2 R = rec[base + lane];
            s = (int)(R.x & SMASK);
            ex = __half2float(__ushort_as_half((unsigned short)(R.y & 0xFFFFu)));
        }
        int j = 0;
        for (; j + 4 <= cnt; j += 4) {
            int s0 = __shfl(s, j), s1 = __shfl(s, j + 1), s2 = __shfl(s, j + 2), s3 = __shfl(s, j + 3);
            float e0 = __shfl(ex, j), e1 = __shfl(ex, j + 1), e2 = __shfl(ex, j + 2), e3 = __shfl(ex, j + 3);
            float h0 = __half2float(hx[(size_t)s0 * 64 + lane]);
            float h1v = __half2float(hx[(size_t)s1 * 64 + lane]);
            float h2 = __half2float(hx[(size_t)s2 * 64 + lane]);
            float h3 = __half2float(hx[(size_t)s3 * 64 + lane]);
            r += e0 * h0; r += e1 * h1v; r += e2 * h2; r += e3 * h3;
            den += e0 + e1 + e2 + e3;
        }
        for (; j < cnt; ++j) {
            int sj = __shfl(s, j); float ej = __shfl(ex, j);
            r += ej * __half2float(hx[(size_t)sj * 64 + lane]);
            den += ej;
        }
    }
    float al = aS[n] + aD[n];
    al = al > 0.f ? al : 0.2f * al;
    float exl = __expf(al);
    float hself = __half2float(hx[(size_t)n * 64 + lane]);
    float val = (r + exl * hself) / (den + exl) + b[lane];
    h1[(size_t)n * 64 + lane] = val > 0.f ? val : expm1f(val);
}

// ---- layer-2 node transform: hx2 = h1 @ W2 (64->32), alpha_s/d ----
__global__ __launch_bounds__(256) void k_node2(
    const float* __restrict__ h1, const float* __restrict__ W,
    const float* __restrict__ a_s, const float* __restrict__ a_d,
    float* __restrict__ hx, float* __restrict__ aS, float* __restrict__ aD, int n_nodes)
{
    __shared__ float Wl[64 * 32];
    __shared__ float xs[8][64];
    int tid = threadIdx.x;
#pragma unroll
    for (int i = 0; i < 8; ++i) Wl[tid + i * 256] = W[tid + i * 256];
    int n0 = blockIdx.x * 8;
    for (int i = tid; i < 8 * 64; i += 256) {
        int r = i >> 6;
        int n = n0 + r;
        xs[r][i & 63] = (n < n_nodes) ? h1[(size_t)n * 64 + (i & 63)] : 0.f;
    }
    __syncthreads();
    int g = tid >> 5, c = tid & 31;
    int n = n0 + g;
    if (n >= n_nodes) return;
    float h = 0.f;
#pragma unroll
    for (int k = 0; k < 64; ++k) h += xs[g][k] * Wl[k * 32 + c];
    hx[(size_t)n * 32 + c] = h;
    float ps = h * a_s[c], pd = h * a_d[c];
#pragma unroll
    for (int o = 16; o > 0; o >>= 1) { ps += __shfl_xor(ps, o, 32); pd += __shfl_xor(pd, o, 32); }
    if (c == 0) { aS[n] = ps; aD[n] = pd; }
}

// ---- layer-2 pull aggregation over masked nodes only + finalize -> out ----
__global__ __launch_bounds__(256) void k_agg2(
    const int* __restrict__ mask,
    const int* __restrict__ rowptr, const int* __restrict__ rowend,
    const uint2* __restrict__ rec, const float* __restrict__ hx,
    const float* __restrict__ aS, const float* __restrict__ aD,
    const float* __restrict__ b, float* __restrict__ out, int m_cnt)
{
    int wv = threadIdx.x >> 6, lane = threadIdx.x & 63;
    int m = blockIdx.x * 4 + wv;
    if (m >= m_cnt) return;
    int n = mask[m];
    int start = rowptr[n], end = rowend[n];
    float aDn = aD[n];
    int half = lane >> 5, c = lane & 31;
    float r = 0.f, den = 0.f;
    for (int base = start; base < end; base += 64) {
        int cnt = min(end - base, 64);
        int s = 0; float ex = 0.f;
        if (lane < cnt) {
            uint2 R = rec[base + lane];
            s = (int)(R.x & SMASK);
            float ae2 = __half2float(__ushort_as_half((unsigned short)(R.y >> 16)));
            float a = aS[s] + aDn + ae2;
            a = a > 0.f ? a : 0.2f * a;
            ex = __expf(a);
        }
        int j = 0;
        for (; j + 8 <= cnt; j += 8) {
            int j0 = j + half, j2 = j + 2 + half, j4 = j + 4 + half, j6 = j + 6 + half;
            int s0 = __shfl(s, j0), s2v = __shfl(s, j2), s4 = __shfl(s, j4), s6 = __shfl(s, j6);
            float e0 = __shfl(ex, j0), e2 = __shfl(ex, j2), e4 = __shfl(ex, j4), e6 = __shfl(ex, j6);
            r += e0 * hx[(size_t)s0 * 32 + c];
            r += e2 * hx[(size_t)s2v * 32 + c];
            r += e4 * hx[(size_t)s4 * 32 + c];
            r += e6 * hx[(size_t)s6 * 32 + c];
            den += e0 + e2 + e4 + e6;
        }
        for (; j < cnt; j += 2) {
            int jj = j + half;
            if (jj < cnt) {
                int sj = __shfl(s, jj); float ej = __shfl(ex, jj);
                r += ej * hx[(size_t)sj * 32 + c];
                den += ej;
            }
        }
    }
    float ro = __shfl(r, lane ^ 32);
    float do_ = __shfl(den, lane ^ 32);
    r += ro; den += do_;
    if (half == 0) {
        float al = aS[n] + aDn;
        al = al > 0.f ? al : 0.2f * al;
        float exl = __expf(al);
        float val = (r + exl * hx[(size_t)n * 32 + c]) / (den + exl) + b[c];
        out[(size_t)m * 32 + c] = val > 0.f ? val : expm1f(val);
    }
}

extern "C" void kernel_launch(void* const* d_in, const int* in_sizes, int n_in,
                              void* d_out, int out_size, void* d_ws, size_t ws_size,
                              hipStream_t stream) {
    const float* x    = (const float*)d_in[0];
    const int*   ei   = (const int*)d_in[1];
    const int*   mask = (const int*)d_in[2];
    const float* ea   = (const float*)d_in[3];
    const float* W1   = (const float*)d_in[4];
    const float* a_s1 = (const float*)d_in[5];
    const float* a_d1 = (const float*)d_in[6];
    const float* We1  = (const float*)d_in[7];
    const float* a_e1 = (const float*)d_in[8];
    const float* b1   = (const float*)d_in[9];
    const float* W2   = (const float*)d_in[10];
    const float* a_s2 = (const float*)d_in[11];
    const float* a_d2 = (const float*)d_in[12];
    const float* We2  = (const float*)d_in[13];
    const float* a_e2 = (const float*)d_in[14];
    const float* b2   = (const float*)d_in[15];
    const int* src = ei;
    const int* dst = ei + EE;
    float* out = (float*)d_out;

    char* w = (char*)d_ws;
    size_t off = 0;
    auto take = [&](size_t bytes) -> char* {
        char* p = w + off;
        off += (bytes + 255) & ~(size_t)255;
        return p;
    };
    float*  v1       = (float*)take(16 * 4);
    float*  v2       = (float*)take(16 * 4);
    __half* hx1h     = (__half*)take((size_t)NN * 64 * 2);
    float*  aS1      = (float*)take((size_t)NN * 4);
    float*  aD1      = (float*)take((size_t)NN * 4);
    float*  h1       = (float*)take((size_t)NN * 64 * 4);
    float*  hx2      = (float*)take((size_t)NN * 32 * 4);
    float*  aS2      = (float*)take((size_t)NN * 4);
    float*  aD2      = (float*)take((size_t)NN * 4);
    int*    deg      = (int*)take((size_t)NN * 4);
    int*    rowptr   = (int*)take((size_t)NN * 4);
    int*    cur      = (int*)take((size_t)NN * 4);
    int*    bh       = (int*)take((size_t)N_SCAN8 * 4);
    int*    scanned8 = (int*)take((size_t)N_SCAN8 * 4);
    int*    bsum     = (int*)take(256 * 4);
    uint2*  recMid   = (uint2*)take((size_t)EE * 8);
    uint2*  rec      = (uint2*)take((size_t)EE * 8);

    const int nb_deg = (NN + 2047) / 2048;        // 49
    const int nb_bh  = (N_SCAN8 + 2047) / 2048;   // 5

    k_v<<<1, 64, 0, stream>>>(We1, a_e1, We2, a_e2, v1, v2);
    k_node1<<<(NN + 3) / 4, 256, 0, stream>>>(x, W1, a_s1, a_d1, hx1h, aS1, aD1, deg, NN);
    k_deg<<<NBLK, 256, 0, stream>>>(dst, deg, bh, EE);
    // scan deg -> rowptr (+cur copy)
    k_scan1<<<nb_deg, 256, 0, stream>>>(deg, rowptr, bsum, NN);
    k_scan2<<<1, 256, 0, stream>>>(bsum, nb_deg);
    k_scan3<<<(NN + 255) / 256, 256, 0, stream>>>(rowptr, bsum, cur, NN);
    // scan bh -> scanned8 (per-(bucket,block) segment bases)
    k_scan1<<<nb_bh, 256, 0, stream>>>(bh, scanned8, bsum, N_SCAN8);
    k_scan2<<<1, 256, 0, stream>>>(bsum, nb_bh);
    k_scan3b<<<(N_SCAN8 + 255) / 256, 256, 0, stream>>>(scanned8, bsum, N_SCAN8);
    // two-level partition
    k_part<<<NBLK, 256, 0, stream>>>(ea, v1, v2, src, dst, aS1, aD1, scanned8, recMid, EE);
    k_place<<<8 * SPLITS, 256, 0, stream>>>(scanned8, recMid, cur, rec, EE);
    // aggregation + layer 2
    k_agg1<<<8 * (BWID / 4), 256, 0, stream>>>(rowptr, cur, rec, hx1h, aS1, aD1, b1, h1);
    k_node2<<<(NN + 7) / 8, 256, 0, stream>>>(h1, W2, a_s2, a_d2, hx2, aS2, aD2, NN);
    k_agg2<<<(MM + 3) / 4, 256, 0, stream>>>(mask, rowptr, cur, rec, hx2, aS2, aD2, b2, out, MM);
}

// Round 9
// 236.973 us; speedup vs baseline: 4.4873x; 1.4765x over previous
//
#include <hip/hip_runtime.h>
#include <hip/hip_bf16.h>
#include <hip/hip_fp16.h>
#include <math.h>

#define NN 100000
#define EE 1600000
#define MM 20000
#define EPB 1536                        // edges per partition block (multiple of 256)
#define NBLK ((EE + EPB - 1) / EPB)     // 1042 partition blocks
#define NBC 250                         // coarse dst buckets
#define BWC 400                         // nodes per bucket (250*400 = 100000 exactly)
#define N_SCAN (NBC * NBLK + 1)         // 260501 (+ sentinel)
#define SMASK 0x1FFFF                   // low 17 bits: src id

// ---- tiny: v1[16] = We1 @ a_e1 (64), v2[16] = We2 @ a_e2 (32) ----
__global__ void k_v(const float* __restrict__ We1, const float* __restrict__ ae1v,
                    const float* __restrict__ We2, const float* __restrict__ ae2v,
                    float* __restrict__ v1, float* __restrict__ v2) {
    int t = threadIdx.x;
    if (t < 16) {
        float s = 0.f;
        for (int c = 0; c < 64; ++c) s += We1[t * 64 + c] * ae1v[c];
        v1[t] = s;
    } else if (t < 32) {
        int r = t - 16;
        float s = 0.f;
        for (int c = 0; c < 32; ++c) s += We2[r * 32 + c] * ae2v[c];
        v2[r] = s;
    }
}

// ---- layer-1 node transform: hx1 (fp16) = x @ W1, alpha_s/d ----
__global__ __launch_bounds__(256) void k_node1(
    const float* __restrict__ x, const float* __restrict__ W,
    const float* __restrict__ a_s, const float* __restrict__ a_d,
    __half* __restrict__ hx, float* __restrict__ aS, float* __restrict__ aD,
    int n_nodes)
{
    __shared__ float Wl[64 * 64];
    __shared__ float xs[4][64];
    int tid = threadIdx.x;
#pragma unroll
    for (int i = 0; i < 16; ++i) Wl[tid + i * 256] = W[tid + i * 256];
    int wv = tid >> 6, lane = tid & 63;
    int n = blockIdx.x * 4 + wv;
    bool act = (n < n_nodes);
    if (act) xs[wv][lane] = x[(size_t)n * 64 + lane];
    __syncthreads();
    if (!act) return;
    float h = 0.f;
#pragma unroll
    for (int k = 0; k < 64; ++k) h += xs[wv][k] * Wl[k * 64 + lane];
    hx[(size_t)n * 64 + lane] = __float2half(h);
    float ps = h * a_s[lane];
    float pd = h * a_d[lane];
#pragma unroll
    for (int o = 32; o > 0; o >>= 1) { ps += __shfl_xor(ps, o); pd += __shfl_xor(pd, o); }
    if (lane == 0) { aS[n] = ps; aD[n] = pd; }
}

// ---- per-(bucket,block) histogram via LDS (no global atomics) ----
__global__ __launch_bounds__(256) void k_bh(const int* __restrict__ dst,
                                            int* __restrict__ bh, int E) {
    __shared__ int hl[NBC];
    int tid = threadIdx.x, blk = blockIdx.x;
    for (int j = tid; j < NBC; j += 256) hl[j] = 0;
    __syncthreads();
    int e0 = blk * EPB, e1 = min(E, e0 + EPB);
    for (int e = e0 + tid; e < e1; e += 256) atomicAdd(&hl[dst[e] / BWC], 1);
    __syncthreads();
    for (int j = tid; j < NBC; j += 256) bh[j * NBLK + blk] = hl[j];
    if (blk == 0 && tid == 0) bh[NBC * NBLK] = 0;   // sentinel -> scan total == E
}

// ---- scan kernels: exclusive prefix (2048 elems/block) ----
__global__ __launch_bounds__(256) void k_scan1(const int* __restrict__ deg, int* __restrict__ pre,
                                               int* __restrict__ bsum, int n) {
    __shared__ int wsum[4];
    int t = threadIdx.x;
    int base = blockIdx.x * 2048 + t * 8;
    int v[8]; int s = 0;
#pragma unroll
    for (int i = 0; i < 8; ++i) { int idx = base + i; int d = (idx < n) ? deg[idx] : 0; v[i] = s; s += d; }
    int lane = t & 63, wv = t >> 6;
    int incl = s;
#pragma unroll
    for (int off = 1; off < 64; off <<= 1) { int y = __shfl_up(incl, off); if (lane >= off) incl += y; }
    if (lane == 63) wsum[wv] = incl;
    __syncthreads();
    int woff = 0;
    for (int w = 0; w < wv; ++w) woff += wsum[w];
    int texcl = woff + incl - s;
#pragma unroll
    for (int i = 0; i < 8; ++i) { int idx = base + i; if (idx < n) pre[idx] = texcl + v[i]; }
    if (t == 255) bsum[blockIdx.x] = woff + incl;
}

__global__ __launch_bounds__(256) void k_scan2(int* __restrict__ bsum, int nb) {
    __shared__ int ws[4];
    int t = threadIdx.x, lane = t & 63, wv = t >> 6;
    int x = (t < nb) ? bsum[t] : 0;
    int incl = x;
#pragma unroll
    for (int off = 1; off < 64; off <<= 1) { int y = __shfl_up(incl, off); if (lane >= off) incl += y; }
    if (lane == 63) ws[wv] = incl;
    __syncthreads();
    int woff = 0;
    for (int w = 0; w < wv; ++w) woff += ws[w];
    if (t < nb) bsum[t] = woff + incl - x;
}

__global__ void k_scan3b(int* __restrict__ pre, const int* __restrict__ bsum, int n) {
    int i = blockIdx.x * 256 + threadIdx.x;
    if (i < n) pre[i] += bsum[i >> 11];
}

// ---- pass 1: edge dots + exp(alpha1); scatter into 250 coarse dst buckets,
//      block-owned segments, positions from LDS cursors (no global atomics) ----
__global__ __launch_bounds__(256) void k_part(
    const float* __restrict__ ea, const float* __restrict__ v1, const float* __restrict__ v2,
    const int* __restrict__ src, const int* __restrict__ dst,
    const float* __restrict__ aS1, const float* __restrict__ aD1,
    const int* __restrict__ scanned, uint2* __restrict__ recMid, int E)
{
    __shared__ int lcur[NBC];
    int tid = threadIdx.x, blk = blockIdx.x;
    for (int j = tid; j < NBC; j += 256) lcur[j] = scanned[j * NBLK + blk];
    __syncthreads();
    const float4* v14 = (const float4*)v1;
    const float4* v24 = (const float4*)v2;
    float4 va0 = v14[0], va1 = v14[1], va2 = v14[2], va3 = v14[3];
    float4 vb0 = v24[0], vb1 = v24[1], vb2 = v24[2], vb3 = v24[3];
    int e0 = blk * EPB, e1 = min(E, e0 + EPB);
    for (int e = e0 + tid; e < e1; e += 256) {
        const float4* p4 = (const float4*)(ea + (size_t)e * 16);
        float4 q0 = p4[0], q1 = p4[1], q2 = p4[2], q3 = p4[3];
        float s1 = q0.x * va0.x + q0.y * va0.y + q0.z * va0.z + q0.w * va0.w
                 + q1.x * va1.x + q1.y * va1.y + q1.z * va1.z + q1.w * va1.w
                 + q2.x * va2.x + q2.y * va2.y + q2.z * va2.z + q2.w * va2.w
                 + q3.x * va3.x + q3.y * va3.y + q3.z * va3.z + q3.w * va3.w;
        float s2 = q0.x * vb0.x + q0.y * vb0.y + q0.z * vb0.z + q0.w * vb0.w
                 + q1.x * vb1.x + q1.y * vb1.y + q1.z * vb1.z + q1.w * vb1.w
                 + q2.x * vb2.x + q2.y * vb2.y + q2.z * vb2.z + q2.w * vb2.w
                 + q3.x * vb3.x + q3.y * vb3.y + q3.z * vb3.z + q3.w * vb3.w;
        int s = src[e], d = dst[e];
        float a = aS1[s] + aD1[d] + s1;
        a = a > 0.f ? a : 0.2f * a;
        float ex = __expf(a);
        int b = d / BWC;
        int dloc = d - b * BWC;                       // < 400, 9 bits
        unsigned lo = (unsigned)s | ((unsigned)dloc << 17);
        unsigned hi = (unsigned)__half_as_ushort(__float2half(ex))
                    | ((unsigned)__half_as_ushort(__float2half(s2)) << 16);
        int pos = atomicAdd(&lcur[b], 1);
        recMid[pos] = make_uint2(lo, hi);
    }
}

// ---- pass 2: one block per bucket: LDS hist -> LDS scan -> rowptr -> place.
//      Zero global atomics; all writes coalesced or inside a 50KB window. ----
__global__ __launch_bounds__(256) void k_build(
    const int* __restrict__ scanned, const uint2* __restrict__ recMid,
    int* __restrict__ rowptr, uint2* __restrict__ rec, int E)
{
    __shared__ int hist[BWC];
    __shared__ int lofs[BWC];
    __shared__ int wsum[4];
    int tid = threadIdx.x, b = blockIdx.x;
    int B0 = scanned[b * NBLK];
    int B1 = scanned[(b + 1) * NBLK];                 // b==NBC-1 hits sentinel == E
    for (int j = tid; j < BWC; j += 256) hist[j] = 0;
    __syncthreads();
    for (int i = B0 + tid; i < B1; i += 256) atomicAdd(&hist[recMid[i].x >> 17], 1);
    __syncthreads();
    // exclusive scan over hist[0..BWC) -> lofs (2 consecutive elems per thread)
    int lane = tid & 63, wv = tid >> 6;
    int i0 = 2 * tid, i1 = 2 * tid + 1;
    int a0 = (i0 < BWC) ? hist[i0] : 0;
    int a1 = (i1 < BWC) ? hist[i1] : 0;
    int s = a0 + a1;
    int incl = s;
#pragma unroll
    for (int off = 1; off < 64; off <<= 1) { int y = __shfl_up(incl, off); if (lane >= off) incl += y; }
    if (lane == 63) wsum[wv] = incl;
    __syncthreads();
    int woff = 0;
    for (int w = 0; w < wv; ++w) woff += wsum[w];
    int base = woff + incl - s;
    if (i0 < BWC) lofs[i0] = base;
    if (i1 < BWC) lofs[i1] = base + a0;
    __syncthreads();
    // rowptr for this bucket (coalesced)
    for (int j = tid; j < BWC; j += 256) rowptr[b * BWC + j] = B0 + lofs[j];
    if (b == NBC - 1 && tid == 0) rowptr[NN] = E;
    __syncthreads();
    // place records at exact CSR slots via LDS cursors
    for (int i = B0 + tid; i < B1; i += 256) {
        uint2 r = recMid[i];
        int nl = (int)(r.x >> 17);
        int p = atomicAdd(&lofs[nl], 1);
        rec[B0 + p] = r;
    }
}

// ---- layer-1 pull aggregation + finalize (self-loop, div, bias, elu) -> h1 ----
__global__ __launch_bounds__(256) void k_agg1(
    const int* __restrict__ rowptr,
    const uint2* __restrict__ rec, const __half* __restrict__ hx,
    const float* __restrict__ aS, const float* __restrict__ aD,
    const float* __restrict__ b, float* __restrict__ h1, int n_nodes)
{
    int wv = threadIdx.x >> 6, lane = threadIdx.x & 63;
    int n = blockIdx.x * 4 + wv;
    if (n >= n_nodes) return;
    int start = rowptr[n], end = rowptr[n + 1];
    float r = 0.f, den = 0.f;
    for (int base = start; base < end; base += 64) {
        int cnt = min(end - base, 64);
        int s = 0; float ex = 0.f;
        if (lane < cnt) {
            uint2 R = rec[base + lane];
            s = (int)(R.x & SMASK);
            ex = __half2float(__ushort_as_half((unsigned short)(R.y & 0xFFFFu)));
        }
        int j = 0;
        for (; j + 4 <= cnt; j += 4) {
            int s0 = __shfl(s, j), s1 = __shfl(s, j + 1), s2 = __shfl(s, j + 2), s3 = __shfl(s, j + 3);
            float e0 = __shfl(ex, j), e1 = __shfl(ex, j + 1), e2 = __shfl(ex, j + 2), e3 = __shfl(ex, j + 3);
            float h0 = __half2float(hx[(size_t)s0 * 64 + lane]);
            float h1v = __half2float(hx[(size_t)s1 * 64 + lane]);
            float h2 = __half2float(hx[(size_t)s2 * 64 + lane]);
            float h3 = __half2float(hx[(size_t)s3 * 64 + lane]);
            r += e0 * h0; r += e1 * h1v; r += e2 * h2; r += e3 * h3;
            den += e0 + e1 + e2 + e3;
        }
        for (; j < cnt; ++j) {
            int sj = __shfl(s, j); float ej = __shfl(ex, j);
            r += ej * __half2float(hx[(size_t)sj * 64 + lane]);
            den += ej;
        }
    }
    float al = aS[n] + aD[n];
    al = al > 0.f ? al : 0.2f * al;
    float exl = __expf(al);
    float hself = __half2float(hx[(size_t)n * 64 + lane]);
    float val = (r + exl * hself) / (den + exl) + b[lane];
    h1[(size_t)n * 64 + lane] = val > 0.f ? val : expm1f(val);
}

// ---- layer-2 node transform: hx2 = h1 @ W2 (64->32), alpha_s/d ----
__global__ __launch_bounds__(256) void k_node2(
    const float* __restrict__ h1, const float* __restrict__ W,
    const float* __restrict__ a_s, const float* __restrict__ a_d,
    float* __restrict__ hx, float* __restrict__ aS, float* __restrict__ aD, int n_nodes)
{
    __shared__ float Wl[64 * 32];
    __shared__ float xs[8][64];
    int tid = threadIdx.x;
#pragma unroll
    for (int i = 0; i < 8; ++i) Wl[tid + i * 256] = W[tid + i * 256];
    int n0 = blockIdx.x * 8;
    for (int i = tid; i < 8 * 64; i += 256) {
        int r = i >> 6;
        int n = n0 + r;
        xs[r][i & 63] = (n < n_nodes) ? h1[(size_t)n * 64 + (i & 63)] : 0.f;
    }
    __syncthreads();
    int g = tid >> 5, c = tid & 31;
    int n = n0 + g;
    if (n >= n_nodes) return;
    float h = 0.f;
#pragma unroll
    for (int k = 0; k < 64; ++k) h += xs[g][k] * Wl[k * 32 + c];
    hx[(size_t)n * 32 + c] = h;
    float ps = h * a_s[c], pd = h * a_d[c];
#pragma unroll
    for (int o = 16; o > 0; o >>= 1) { ps += __shfl_xor(ps, o, 32); pd += __shfl_xor(pd, o, 32); }
    if (c == 0) { aS[n] = ps; aD[n] = pd; }
}

// ---- layer-2 pull aggregation over masked nodes only + finalize -> out ----
__global__ __launch_bounds__(256) void k_agg2(
    const int* __restrict__ mask, const int* __restrict__ rowptr,
    const uint2* __restrict__ rec, const float* __restrict__ hx,
    const float* __restrict__ aS, const float* __restrict__ aD,
    const float* __restrict__ b, float* __restrict__ out, int m_cnt)
{
    int wv = threadIdx.x >> 6, lane = threadIdx.x & 63;
    int m = blockIdx.x * 4 + wv;
    if (m >= m_cnt) return;
    int n = mask[m];
    int start = rowptr[n], end = rowptr[n + 1];
    float aDn = aD[n];
    int half = lane >> 5, c = lane & 31;
    float r = 0.f, den = 0.f;
    for (int base = start; base < end; base += 64) {
        int cnt = min(end - base, 64);
        int s = 0; float ex = 0.f;
        if (lane < cnt) {
            uint2 R = rec[base + lane];
            s = (int)(R.x & SMASK);
            float ae2 = __half2float(__ushort_as_half((unsigned short)(R.y >> 16)));
            float a = aS[s] + aDn + ae2;
            a = a > 0.f ? a : 0.2f * a;
            ex = __expf(a);
        }
        int j = 0;
        for (; j + 8 <= cnt; j += 8) {
            int j0 = j + half, j2 = j + 2 + half, j4 = j + 4 + half, j6 = j + 6 + half;
            int s0 = __shfl(s, j0), s2v = __shfl(s, j2), s4 = __shfl(s, j4), s6 = __shfl(s, j6);
            float e0 = __shfl(ex, j0), e2 = __shfl(ex, j2), e4 = __shfl(ex, j4), e6 = __shfl(ex, j6);
            r += e0 * hx[(size_t)s0 * 32 + c];
            r += e2 * hx[(size_t)s2v * 32 + c];
            r += e4 * hx[(size_t)s4 * 32 + c];
            r += e6 * hx[(size_t)s6 * 32 + c];
            den += e0 + e2 + e4 + e6;
        }
        for (; j < cnt; j += 2) {
            int jj = j + half;
            if (jj < cnt) {
                int sj = __shfl(s, jj); float ej = __shfl(ex, jj);
                r += ej * hx[(size_t)sj * 32 + c];
                den += ej;
            }
        }
    }
    float ro = __shfl(r, lane ^ 32);
    float do_ = __shfl(den, lane ^ 32);
    r += ro; den += do_;
    if (half == 0) {
        float al = aS[n] + aDn;
        al = al > 0.f ? al : 0.2f * al;
        float exl = __expf(al);
        float val = (r + exl * hx[(size_t)n * 32 + c]) / (den + exl) + b[c];
        out[(size_t)m * 32 + c] = val > 0.f ? val : expm1f(val);
    }
}

extern "C" void kernel_launch(void* const* d_in, const int* in_sizes, int n_in,
                              void* d_out, int out_size, void* d_ws, size_t ws_size,
                              hipStream_t stream) {
    const float* x    = (const float*)d_in[0];
    const int*   ei   = (const int*)d_in[1];
    const int*   mask = (const int*)d_in[2];
    const float* ea   = (const float*)d_in[3];
    const float* W1   = (const float*)d_in[4];
    const float* a_s1 = (const float*)d_in[5];
    const float* a_d1 = (const float*)d_in[6];
    const float* We1  = (const float*)d_in[7];
    const float* a_e1 = (const float*)d_in[8];
    const float* b1   = (const float*)d_in[9];
    const float* W2   = (const float*)d_in[10];
    const float* a_s2 = (const float*)d_in[11];
    const float* a_d2 = (const float*)d_in[12];
    const float* We2  = (const float*)d_in[13];
    const float* a_e2 = (const float*)d_in[14];
    const float* b2   = (const float*)d_in[15];
    const int* src = ei;
    const int* dst = ei + EE;
    float* out = (float*)d_out;

    char* w = (char*)d_ws;
    size_t off = 0;
    auto take = [&](size_t bytes) -> char* {
        char* p = w + off;
        off += (bytes + 255) & ~(size_t)255;
        return p;
    };
    float*  v1      = (float*)take(16 * 4);
    float*  v2      = (float*)take(16 * 4);
    __half* hx1h    = (__half*)take((size_t)NN * 64 * 2);
    float*  aS1     = (float*)take((size_t)NN * 4);
    float*  aD1     = (float*)take((size_t)NN * 4);
    float*  h1      = (float*)take((size_t)NN * 64 * 4);
    float*  hx2     = (float*)take((size_t)NN * 32 * 4);
    float*  aS2     = (float*)take((size_t)NN * 4);
    float*  aD2     = (float*)take((size_t)NN * 4);
    int*    rowptr  = (int*)take(((size_t)NN + 1) * 4);
    int*    bh      = (int*)take((size_t)N_SCAN * 4);
    int*    scanned = (int*)take((size_t)N_SCAN * 4);
    int*    bsum    = (int*)take(256 * 4);
    uint2*  recMid  = (uint2*)take((size_t)EE * 8);
    uint2*  rec     = (uint2*)take((size_t)EE * 8);

    const int nb_bh = (N_SCAN + 2047) / 2048;     // 128

    k_v<<<1, 64, 0, stream>>>(We1, a_e1, We2, a_e2, v1, v2);
    k_node1<<<(NN + 3) / 4, 256, 0, stream>>>(x, W1, a_s1, a_d1, hx1h, aS1, aD1, NN);
    k_bh<<<NBLK, 256, 0, stream>>>(dst, bh, EE);
    k_scan1<<<nb_bh, 256, 0, stream>>>(bh, scanned, bsum, N_SCAN);
    k_scan2<<<1, 256, 0, stream>>>(bsum, nb_bh);
    k_scan3b<<<(N_SCAN + 255) / 256, 256, 0, stream>>>(scanned, bsum, N_SCAN);
    k_part<<<NBLK, 256, 0, stream>>>(ea, v1, v2, src, dst, aS1, aD1, scanned, recMid, EE);
    k_build<<<NBC, 256, 0, stream>>>(scanned, recMid, rowptr, rec, EE);
    k_agg1<<<(NN + 3) / 4, 256, 0, stream>>>(rowptr, rec, hx1h, aS1, aD1, b1, h1, NN);
    k_node2<<<(NN + 7) / 8, 256, 0, stream>>>(h1, W2, a_s2, a_d2, hx2, aS2, aD2, NN);
    k_agg2<<<(MM + 3) / 4, 256, 0, stream>>>(mask, rowptr, rec, hx2, aS2, aD2, b2, out, MM);
}